// Round 1
// baseline (669.836 us; speedup 1.0000x reference)
//
#include <hip/hip_runtime.h>

#define KNN 30
#define FDIM 64
#define HDIM 64

typedef short s8v __attribute__((ext_vector_type(8)));   // 8 bf16 bit-patterns (4 VGPR)
typedef float f4v __attribute__((ext_vector_type(4)));   // MFMA accumulator

// round-to-nearest-even f32 -> bf16 bits
static __device__ __forceinline__ unsigned short f2bf(float f) {
  unsigned int u = __builtin_bit_cast(unsigned int, f);
  u += 0x7fffu + ((u >> 16) & 1u);
  return (unsigned short)(u >> 16);
}

// XOR swizzle (ushort-index space): byte ^= (row&7)<<4  <=>  idx ^= (row&7)<<3
static __device__ __forceinline__ int swzi(int row, int col, int roww) {
  return (row * roww + col) ^ ((row & 7) << 3);
}

static __device__ __forceinline__ void lds_fence() {
  asm volatile("s_waitcnt lgkmcnt(0)" ::: "memory");
  __builtin_amdgcn_sched_barrier(0);
}

// ---------------- sq[i] = |x_i|^2 ----------------
__global__ __launch_bounds__(256) void sq_kernel(const float* __restrict__ x,
                                                 float* __restrict__ sq) {
  int lane = threadIdx.x & 63;
  int row = blockIdx.x * 4 + (threadIdx.x >> 6);
  float v = x[(size_t)row * FDIM + lane];
  float s = v * v;
#pragma unroll
  for (int off = 32; off; off >>= 1) s += __shfl_xor(s, off);
  if (lane == 0) sq[row] = s;
}

// ---------------- distance tiles: D[row][w] = sq[w] - 2*dot(x_v, x_w) ----------------
// grid (V/64, nrows/64), block 256. Rows are global rows R0+...; each 64-row tile lies
// in a single batch (64 | V).
__global__ __launch_bounds__(256) void dist_kernel(const float* __restrict__ x,
                                                   const float* __restrict__ sq,
                                                   float* __restrict__ D,
                                                   int R0, int V) {
  __shared__ float XvT[FDIM][68];  // [k][row], pad 68: 16B-aligned f4 rows, 2-way banks max
  __shared__ float XwT[FDIM][68];
  int R = R0 + blockIdx.y * 64;
  int b = R / V;
  int v0 = R - b * V;
  int w0 = blockIdx.x * 64;
  const float* xb = x + (size_t)b * V * FDIM;
  int t = threadIdx.x;
  {
    int r = t >> 2;
    int f0 = (t & 3) * 16;
    const float* pv = xb + (size_t)(v0 + r) * FDIM + f0;
    const float* pw = xb + (size_t)(w0 + r) * FDIM + f0;
#pragma unroll
    for (int i = 0; i < 4; ++i) {
      float4 a = *reinterpret_cast<const float4*>(pv + i * 4);
      float4 c = *reinterpret_cast<const float4*>(pw + i * 4);
      int f = f0 + i * 4;
      XvT[f + 0][r] = a.x; XvT[f + 1][r] = a.y; XvT[f + 2][r] = a.z; XvT[f + 3][r] = a.w;
      XwT[f + 0][r] = c.x; XwT[f + 1][r] = c.y; XwT[f + 2][r] = c.z; XwT[f + 3][r] = c.w;
    }
  }
  __syncthreads();
  int tx = t & 15, ty = t >> 4;  // 16x16 threads, 4x4 micro-tile each
  float acc[4][4] = {};
#pragma unroll 8
  for (int k = 0; k < FDIM; ++k) {
    float4 av = *reinterpret_cast<const float4*>(&XvT[k][ty * 4]);
    float4 bv = *reinterpret_cast<const float4*>(&XwT[k][tx * 4]);
    float aa[4] = {av.x, av.y, av.z, av.w};
    float bb[4] = {bv.x, bv.y, bv.z, bv.w};
#pragma unroll
    for (int i = 0; i < 4; ++i)
#pragma unroll
      for (int j = 0; j < 4; ++j) acc[i][j] = fmaf(aa[i], bb[j], acc[i][j]);
  }
  int wbase = w0 + tx * 4;
  float sw[4];
#pragma unroll
  for (int j = 0; j < 4; ++j) sw[j] = sq[(size_t)b * V + wbase + j];
  size_t drow0 = (size_t)(blockIdx.y * 64 + ty * 4);
#pragma unroll
  for (int i = 0; i < 4; ++i) {
    float4 o;
    o.x = sw[0] - 2.0f * acc[i][0];
    o.y = sw[1] - 2.0f * acc[i][1];
    o.z = sw[2] - 2.0f * acc[i][2];
    o.w = sw[3] - 2.0f * acc[i][3];
    *reinterpret_cast<float4*>(&D[(drow0 + i) * (size_t)V + wbase]) = o;
  }
}

// ---------------- top-30 smallest per row (V must be 2048) ----------------
// wave per row; each lane holds 32 values in registers (static indexing only);
// per-lane top-2 cache; lexicographic (val,idx) argmin matches stable lax.top_k.
__global__ __launch_bounds__(256) void topk_kernel(const float* __restrict__ D,
                                                   int* __restrict__ idxout,
                                                   int R0, int nrows, int V) {
  const float FINF = __builtin_inff();
  int wave = threadIdx.x >> 6, lane = threadIdx.x & 63;
  int rowL = blockIdx.x * 4 + wave;
  if (rowL >= nrows) return;
  int R = R0 + rowL;
  int vsel = R - (R / V) * V;  // batch-local self index
  const float* row = D + (size_t)rowL * V;
  float d[32];
#pragma unroll
  for (int s = 0; s < 32; ++s) {
    int w = s * 64 + lane;
    float val = row[w];
    d[s] = (w == vsel) ? FINF : val;
  }
  float v1 = FINF, v2 = FINF;
  int i1 = 0x7fffffff, i2 = 0x7fffffff;
#pragma unroll
  for (int s = 0; s < 32; ++s) {
    float val = d[s]; int w = s * 64 + lane;
    if (val < v1) { v2 = v1; i2 = i1; v1 = val; i1 = w; }
    else if (val < v2) { v2 = val; i2 = w; }
  }
  for (int it = 0; it < KNN; ++it) {
    float bv = v1; int bi = i1;
#pragma unroll
    for (int off = 32; off; off >>= 1) {
      float ov = __shfl_xor(bv, off);
      int oi = __shfl_xor(bi, off);
      if (ov < bv || (ov == bv && oi < bi)) { bv = ov; bi = oi; }
    }
    if (lane == 0) idxout[(size_t)R * KNN + it] = bi;
    if (i1 == bi) {  // this lane won (w-indices unique)
      v1 = v2; i1 = i2; v2 = FINF; i2 = 0x7fffffff;
      if (i1 == 0x7fffffff) {
        // rebuild top-2 among values strictly lex-greater than last extracted (bv,bi)
#pragma unroll
        for (int s = 0; s < 32; ++s) {
          float val = d[s]; int w = s * 64 + lane;
          bool ok = (val > bv) || (val == bv && w > bi);
          if (ok) {
            if (val < v1) { v2 = v1; i2 = i1; v1 = val; i1 = w; }
            else if (val < v2) { v2 = val; i2 = w; }
          }
        }
      }
    }
  }
}

// ---------------- fused edge-MLP + max aggregation ----------------
// block = 256 (4 waves), 16 vertices/block, wave processes 4 vertices sequentially.
// Per vertex: E[32][128] bf16 (XOR-swizzled, per-wave 8KB scratch) -> 3 MFMA layers -> max.
__global__ __launch_bounds__(256) void mlp_kernel(const float* __restrict__ x,
                                                  const int* __restrict__ idx,
                                                  const float* __restrict__ W1,
                                                  const float* __restrict__ b1,
                                                  const float* __restrict__ W2,
                                                  const float* __restrict__ b2,
                                                  const float* __restrict__ W3,
                                                  const float* __restrict__ b3,
                                                  float* __restrict__ out, int V) {
  __shared__ __align__(16) unsigned short sW1T[2 * FDIM * HDIM];  // [64][128] W1^T
  __shared__ __align__(16) unsigned short sW2T[HDIM * HDIM];      // [64][64]  W2^T
  __shared__ __align__(16) unsigned short sW3T[HDIM * HDIM];      // [64][64]  W3^T
  __shared__ __align__(16) unsigned short sScr[4][4096];          // 8KB / wave
  int t = threadIdx.x;
  for (int e = t; e < 2 * FDIM * HDIM; e += 256) {
    int i = e >> 6, j = e & 63;                // W1[i][j], i<128
    sW1T[swzi(j, i, 128)] = f2bf(W1[e]);
  }
  for (int e = t; e < HDIM * HDIM; e += 256) {
    int i = e >> 6, j = e & 63;
    sW2T[swzi(j, i, 64)] = f2bf(W2[e]);
    sW3T[swzi(j, i, 64)] = f2bf(W3[e]);
  }
  __syncthreads();

  int wv = t >> 6, lane = t & 63;
  int q = lane >> 4, cl = lane & 15;
  unsigned short* scr = &sScr[wv][0];
  unsigned int* scr32 = reinterpret_cast<unsigned int*>(scr);
  float bias1[4], bias2[4], bias3[4];
#pragma unroll
  for (int nt = 0; nt < 4; ++nt) {
    bias1[nt] = b1[nt * 16 + cl];
    bias2[nt] = b2[nt * 16 + cl];
    bias3[nt] = b3[nt * 16 + cl];
  }

  for (int vi = 0; vi < 4; ++vi) {
    int v = blockIdx.x * 16 + wv * 4 + vi;
    int b = v / V;
    int vloc = v - b * V;
    const float* xb = x + (size_t)b * V * FDIM;
    int hl = lane & 31;
    float2 c2 = *reinterpret_cast<const float2*>(xb + (size_t)vloc * FDIM + 2 * hl);
    int myidx = (lane < KNN) ? idx[(size_t)v * KNN + lane] : 0;

    // build E rows: cols [0,64) = c, [64,128) = c - n   (rows 30,31 duplicate edge 29)
#pragma unroll 4
    for (int r = 0; r < 32; ++r) {
      int kk = (r < KNN) ? r : (KNN - 1);
      int nb = __shfl(myidx, kk);
      float2 n2 = *reinterpret_cast<const float2*>(xb + (size_t)nb * FDIM + 2 * hl);
      float e0, e1;
      if (lane < 32) { e0 = c2.x;        e1 = c2.y; }
      else           { e0 = c2.x - n2.x; e1 = c2.y - n2.y; }
      unsigned int pk = (unsigned int)f2bf(e0) | ((unsigned int)f2bf(e1) << 16);
      scr32[(r * 64 + lane) ^ ((r & 7) << 2)] = pk;  // same swizzle, uint-index form
    }
    lds_fence();

    // ---- layer 1: [32x128] @ [128x64] ----
    s8v af[2][4];
#pragma unroll
    for (int mt = 0; mt < 2; ++mt)
#pragma unroll
      for (int ks = 0; ks < 4; ++ks)
        af[mt][ks] = *reinterpret_cast<const s8v*>(&scr[swzi(mt * 16 + cl, ks * 32 + q * 8, 128)]);
    f4v acc[2][4];
#pragma unroll
    for (int mt = 0; mt < 2; ++mt)
#pragma unroll
      for (int nt = 0; nt < 4; ++nt) {
        f4v a0 = {bias1[nt], bias1[nt], bias1[nt], bias1[nt]};
        acc[mt][nt] = a0;
      }
#pragma unroll
    for (int ks = 0; ks < 4; ++ks)
#pragma unroll
      for (int nt = 0; nt < 4; ++nt) {
        s8v wf = *reinterpret_cast<const s8v*>(&sW1T[swzi(nt * 16 + cl, ks * 32 + q * 8, 128)]);
        acc[0][nt] = __builtin_amdgcn_mfma_f32_16x16x32_bf16(af[0][ks], wf, acc[0][nt], 0, 0, 0);
        acc[1][nt] = __builtin_amdgcn_mfma_f32_16x16x32_bf16(af[1][ks], wf, acc[1][nt], 0, 0, 0);
      }
    lds_fence();
    // relu -> H1 at scr[0..2048)
#pragma unroll
    for (int mt = 0; mt < 2; ++mt)
#pragma unroll
      for (int nt = 0; nt < 4; ++nt)
#pragma unroll
        for (int i = 0; i < 4; ++i) {
          float hv = fmaxf(acc[mt][nt][i], 0.0f);
          scr[swzi(mt * 16 + q * 4 + i, nt * 16 + cl, 64)] = f2bf(hv);
        }
    lds_fence();

    // ---- layer 2: [32x64] @ [64x64] ----
    s8v af2[2][2];
#pragma unroll
    for (int mt = 0; mt < 2; ++mt)
#pragma unroll
      for (int ks = 0; ks < 2; ++ks)
        af2[mt][ks] = *reinterpret_cast<const s8v*>(&scr[swzi(mt * 16 + cl, ks * 32 + q * 8, 64)]);
    f4v acc2[2][4];
#pragma unroll
    for (int mt = 0; mt < 2; ++mt)
#pragma unroll
      for (int nt = 0; nt < 4; ++nt) {
        f4v a0 = {bias2[nt], bias2[nt], bias2[nt], bias2[nt]};
        acc2[mt][nt] = a0;
      }
#pragma unroll
    for (int ks = 0; ks < 2; ++ks)
#pragma unroll
      for (int nt = 0; nt < 4; ++nt) {
        s8v wf = *reinterpret_cast<const s8v*>(&sW2T[swzi(nt * 16 + cl, ks * 32 + q * 8, 64)]);
        acc2[0][nt] = __builtin_amdgcn_mfma_f32_16x16x32_bf16(af2[0][ks], wf, acc2[0][nt], 0, 0, 0);
        acc2[1][nt] = __builtin_amdgcn_mfma_f32_16x16x32_bf16(af2[1][ks], wf, acc2[1][nt], 0, 0, 0);
      }
    lds_fence();
    // relu -> H2 at scr[2048..4096)
#pragma unroll
    for (int mt = 0; mt < 2; ++mt)
#pragma unroll
      for (int nt = 0; nt < 4; ++nt)
#pragma unroll
        for (int i = 0; i < 4; ++i) {
          float hv = fmaxf(acc2[mt][nt][i], 0.0f);
          scr[2048 + swzi(mt * 16 + q * 4 + i, nt * 16 + cl, 64)] = f2bf(hv);
        }
    lds_fence();

    // ---- layer 3: [32x64] @ [64x64] ----
    s8v af3[2][2];
#pragma unroll
    for (int mt = 0; mt < 2; ++mt)
#pragma unroll
      for (int ks = 0; ks < 2; ++ks)
        af3[mt][ks] = *reinterpret_cast<const s8v*>(&scr[2048 + swzi(mt * 16 + cl, ks * 32 + q * 8, 64)]);
    f4v acc3[2][4];
#pragma unroll
    for (int mt = 0; mt < 2; ++mt)
#pragma unroll
      for (int nt = 0; nt < 4; ++nt) {
        f4v a0 = {bias3[nt], bias3[nt], bias3[nt], bias3[nt]};
        acc3[mt][nt] = a0;
      }
#pragma unroll
    for (int ks = 0; ks < 2; ++ks)
#pragma unroll
      for (int nt = 0; nt < 4; ++nt) {
        s8v wf = *reinterpret_cast<const s8v*>(&sW3T[swzi(nt * 16 + cl, ks * 32 + q * 8, 64)]);
        acc3[0][nt] = __builtin_amdgcn_mfma_f32_16x16x32_bf16(af3[0][ks], wf, acc3[0][nt], 0, 0, 0);
        acc3[1][nt] = __builtin_amdgcn_mfma_f32_16x16x32_bf16(af3[1][ks], wf, acc3[1][nt], 0, 0, 0);
      }

    // relu + max over the 32 edge rows (relu>=0, so 0-init == max of relus)
    float m[4] = {0.0f, 0.0f, 0.0f, 0.0f};
#pragma unroll
    for (int nt = 0; nt < 4; ++nt)
#pragma unroll
      for (int mt = 0; mt < 2; ++mt)
#pragma unroll
        for (int i = 0; i < 4; ++i) m[nt] = fmaxf(m[nt], acc3[mt][nt][i]);
#pragma unroll
    for (int nt = 0; nt < 4; ++nt) {
      m[nt] = fmaxf(m[nt], __shfl_xor(m[nt], 16));
      m[nt] = fmaxf(m[nt], __shfl_xor(m[nt], 32));
    }
    float outv = (q == 0) ? m[0] : (q == 1) ? m[1] : (q == 2) ? m[2] : m[3];
    out[(size_t)v * HDIM + lane] = outv;
  }
}

extern "C" void kernel_launch(void* const* d_in, const int* in_sizes, int n_in,
                              void* d_out, int out_size, void* d_ws, size_t ws_size,
                              hipStream_t stream) {
  const float* x  = (const float*)d_in[0];
  const float* W1 = (const float*)d_in[2];
  const float* b1 = (const float*)d_in[3];
  const float* W2 = (const float*)d_in[4];
  const float* b2 = (const float*)d_in[5];
  const float* W3 = (const float*)d_in[6];
  const float* b3 = (const float*)d_in[7];
  float* out = (float*)d_out;
  int N = in_sizes[0] / FDIM;      // 32768
  int B = in_sizes[1] - 1;         // 16
  int V = N / B;                   // 2048

  char* ws = (char*)d_ws;
  float* sqbuf = (float*)ws;
  size_t off = (size_t)N * sizeof(float);
  int* idxbuf = (int*)(ws + off);
  off += (size_t)N * KNN * sizeof(int);
  off = (off + 255) & ~(size_t)255;
  float* Dbuf = (float*)(ws + off);
  size_t dcap = (ws_size > off) ? (ws_size - off) : 0;
  long long capRows = (long long)(dcap / ((size_t)V * sizeof(float)));
  capRows &= ~63LL;
  if (capRows > N) capRows = N;
  if (capRows < 64) capRows = 64;  // requires ws_size >= ~4.7 MB

  sq_kernel<<<N / 4, 256, 0, stream>>>(x, sqbuf);
  for (int R0 = 0; R0 < N; R0 += (int)capRows) {
    int nr = N - R0;
    if (nr > capRows) nr = (int)capRows;
    dim3 g(V / 64, nr / 64);
    dist_kernel<<<g, 256, 0, stream>>>(x, sqbuf, Dbuf, R0, V);
    topk_kernel<<<nr / 4, 256, 0, stream>>>(Dbuf, idxbuf, R0, nr, V);
  }
  mlp_kernel<<<N / 16, 256, 0, stream>>>(x, idxbuf, W1, b1, W2, b2, W3, b3, out, V);
}

// Round 2
// 369.637 us; speedup vs baseline: 1.8121x; 1.8121x over previous
//
#include <hip/hip_runtime.h>

#define KNN 30
#define FDIM 64
#define HDIM 64

typedef short s8v __attribute__((ext_vector_type(8)));   // 8 bf16 bit-patterns (4 VGPR)
typedef float f4v __attribute__((ext_vector_type(4)));   // MFMA accumulator

// round-to-nearest-even f32 -> bf16 bits
static __device__ __forceinline__ unsigned short f2bf(float f) {
  unsigned int u = __builtin_bit_cast(unsigned int, f);
  u += 0x7fffu + ((u >> 16) & 1u);
  return (unsigned short)(u >> 16);
}

// f32 bits -> order-preserving u32 (asc float order == asc uint order)
static __device__ __forceinline__ unsigned int f2sort(float f) {
  unsigned int u = __builtin_bit_cast(unsigned int, f);
  unsigned int m = (unsigned int)(((int)u) >> 31) | 0x80000000u;
  return u ^ m;
}

// XOR swizzle (ushort-index space): byte ^= (row&7)<<4  <=>  idx ^= (row&7)<<3
static __device__ __forceinline__ int swzi(int row, int col, int roww) {
  return (row * roww + col) ^ ((row & 7) << 3);
}

static __device__ __forceinline__ void lds_fence() {
  asm volatile("s_waitcnt lgkmcnt(0)" ::: "memory");
  __builtin_amdgcn_sched_barrier(0);
}

// ---------------- sq[i] = |x_i|^2 ----------------
__global__ __launch_bounds__(256) void sq_kernel(const float* __restrict__ x,
                                                 float* __restrict__ sq) {
  int lane = threadIdx.x & 63;
  int row = blockIdx.x * 4 + (threadIdx.x >> 6);
  float v = x[(size_t)row * FDIM + lane];
  float s = v * v;
#pragma unroll
  for (int off = 32; off; off >>= 1) s += __shfl_xor(s, off);
  if (lane == 0) sq[row] = s;
}

// ---------------- distance tiles: D[row][w] = sq[w] - 2*dot(x_v, x_w) ----------------
__global__ __launch_bounds__(256) void dist_kernel(const float* __restrict__ x,
                                                   const float* __restrict__ sq,
                                                   float* __restrict__ D,
                                                   int R0, int V) {
  __shared__ float XvT[FDIM][68];
  __shared__ float XwT[FDIM][68];
  int R = R0 + blockIdx.y * 64;
  int b = R / V;
  int v0 = R - b * V;
  int w0 = blockIdx.x * 64;
  const float* xb = x + (size_t)b * V * FDIM;
  int t = threadIdx.x;
  {
    int r = t >> 2;
    int f0 = (t & 3) * 16;
    const float* pv = xb + (size_t)(v0 + r) * FDIM + f0;
    const float* pw = xb + (size_t)(w0 + r) * FDIM + f0;
#pragma unroll
    for (int i = 0; i < 4; ++i) {
      float4 a = *reinterpret_cast<const float4*>(pv + i * 4);
      float4 c = *reinterpret_cast<const float4*>(pw + i * 4);
      int f = f0 + i * 4;
      XvT[f + 0][r] = a.x; XvT[f + 1][r] = a.y; XvT[f + 2][r] = a.z; XvT[f + 3][r] = a.w;
      XwT[f + 0][r] = c.x; XwT[f + 1][r] = c.y; XwT[f + 2][r] = c.z; XwT[f + 3][r] = c.w;
    }
  }
  __syncthreads();
  int tx = t & 15, ty = t >> 4;
  float acc[4][4] = {};
#pragma unroll 8
  for (int k = 0; k < FDIM; ++k) {
    float4 av = *reinterpret_cast<const float4*>(&XvT[k][ty * 4]);
    float4 bv = *reinterpret_cast<const float4*>(&XwT[k][tx * 4]);
    float aa[4] = {av.x, av.y, av.z, av.w};
    float bb[4] = {bv.x, bv.y, bv.z, bv.w};
#pragma unroll
    for (int i = 0; i < 4; ++i)
#pragma unroll
      for (int j = 0; j < 4; ++j) acc[i][j] = fmaf(aa[i], bb[j], acc[i][j]);
  }
  int wbase = w0 + tx * 4;
  float sw[4];
#pragma unroll
  for (int j = 0; j < 4; ++j) sw[j] = sq[(size_t)b * V + wbase + j];
  size_t drow0 = (size_t)(blockIdx.y * 64 + ty * 4);
#pragma unroll
  for (int i = 0; i < 4; ++i) {
    float4 o;
    o.x = sw[0] - 2.0f * acc[i][0];
    o.y = sw[1] - 2.0f * acc[i][1];
    o.z = sw[2] - 2.0f * acc[i][2];
    o.w = sw[3] - 2.0f * acc[i][3];
    *reinterpret_cast<float4*>(&D[(drow0 + i) * (size_t)V + wbase]) = o;
  }
}

// ---------------- top-30 smallest per row via threshold+compact+bitonic ----------------
// One wave per row (V must be 2048). Shifted distance makes self the strict row minimum,
// so we select the 31 smallest and drop rank 0 (== reference's drop-self).
__global__ __launch_bounds__(256) void topk_kernel(const float* __restrict__ D,
                                                   int* __restrict__ idxout,
                                                   int R0, int nrows, int V) {
  __shared__ unsigned long long cand[4][64];  // per-wave candidate pool
  int wave = threadIdx.x >> 6, lane = threadIdx.x & 63;
  int rowL = blockIdx.x * 4 + wave;
  if (rowL >= nrows) return;  // no __syncthreads below (per-wave LDS only)
  int R = R0 + rowL;
  const float* row = D + (size_t)rowL * (size_t)V;

  // load 32 values/lane, convert to sortable u32. value r lives at col w(r).
  unsigned int sv[32];
  int wb = lane * 4;
#pragma unroll
  for (int s = 0; s < 8; ++s) {
    float4 f = reinterpret_cast<const float4*>(row)[s * 64 + lane];
    sv[s * 4 + 0] = f2sort(f.x);
    sv[s * 4 + 1] = f2sort(f.y);
    sv[s * 4 + 2] = f2sort(f.z);
    sv[s * 4 + 3] = f2sort(f.w);
  }
  // w(r) = (r>>2)*256 + lane*4 + (r&3)

  // per-lane min (u32 order == float order)
  unsigned int mn = sv[0];
#pragma unroll
  for (int r = 1; r < 32; ++r) mn = min(mn, sv[r]);

  // bitonic-64 sort of lane minima; tau = 31st smallest lane-min >= true 31st value
  unsigned int srt = mn;
#pragma unroll
  for (int k = 2; k <= 64; k <<= 1) {
#pragma unroll
    for (int j = k >> 1; j > 0; j >>= 1) {
      unsigned int o = __shfl_xor(srt, j);
      bool keep_min = ((lane & k) == 0) == ((lane & j) == 0);
      bool less = srt < o;
      srt = (keep_min == less) ? srt : o;
    }
  }
  unsigned int tau = __shfl(srt, 30);

  // compact all values <= tau into LDS (ballot/mbcnt slots); count total
  int base = 0;
#pragma unroll
  for (int r = 0; r < 32; ++r) {
    bool pred = sv[r] <= tau;
    unsigned long long m = __ballot(pred);
    unsigned int off = __builtin_amdgcn_mbcnt_lo((unsigned int)m, 0u);
    off = __builtin_amdgcn_mbcnt_hi((unsigned int)(m >> 32), off);
    int slot = base + (int)off;
    if (pred && slot < 64) {
      unsigned int w = (unsigned int)((r >> 2) * 256 + wb + (r & 3));
      cand[wave][slot] = ((unsigned long long)sv[r] << 32) | w;
    }
    base += (int)__popcll(m);
  }

  if (base <= 64) {
    lds_fence();
    unsigned long long key = cand[wave][lane];
    if (lane >= base) key = ~0ULL;
    // bitonic-64 on u64 keys: exact (value asc, index asc) == stable lax.top_k order
#pragma unroll
    for (int k = 2; k <= 64; k <<= 1) {
#pragma unroll
      for (int j = k >> 1; j > 0; j >>= 1) {
        unsigned long long o = __shfl_xor(key, j);
        bool keep_min = ((lane & k) == 0) == ((lane & j) == 0);
        bool less = key < o;
        key = (keep_min == less) ? key : o;
      }
    }
    if (lane >= 1 && lane <= KNN)
      idxout[(size_t)R * KNN + (lane - 1)] = (int)(unsigned int)key;
  } else {
    // exact fallback (pathological clustering only): sequential argmin with removal mask
    unsigned int removed = 0;
    for (int it = 0; it < KNN + 1; ++it) {
      unsigned long long m = ~0ULL;
#pragma unroll
      for (int r = 0; r < 32; ++r) {
        unsigned long long key =
            ((unsigned long long)sv[r] << 32) | (unsigned int)((r >> 2) * 256 + wb + (r & 3));
        bool alive = ((removed >> r) & 1u) == 0u;
        if (alive && key < m) m = key;
      }
      unsigned long long g = m;
#pragma unroll
      for (int off = 32; off; off >>= 1) {
        unsigned long long o = __shfl_xor(g, off);
        g = (o < g) ? o : g;
      }
      if (it > 0 && lane == 0) idxout[(size_t)R * KNN + (it - 1)] = (int)(unsigned int)g;
#pragma unroll
      for (int r = 0; r < 32; ++r) {
        unsigned long long key =
            ((unsigned long long)sv[r] << 32) | (unsigned int)((r >> 2) * 256 + wb + (r & 3));
        if (key == g) removed |= (1u << r);
      }
    }
  }
}

// ---------------- fused edge-MLP + max aggregation ----------------
__global__ __launch_bounds__(256) void mlp_kernel(const float* __restrict__ x,
                                                  const int* __restrict__ idx,
                                                  const float* __restrict__ W1,
                                                  const float* __restrict__ b1,
                                                  const float* __restrict__ W2,
                                                  const float* __restrict__ b2,
                                                  const float* __restrict__ W3,
                                                  const float* __restrict__ b3,
                                                  float* __restrict__ out, int V) {
  __shared__ __align__(16) unsigned short sW1T[2 * FDIM * HDIM];
  __shared__ __align__(16) unsigned short sW2T[HDIM * HDIM];
  __shared__ __align__(16) unsigned short sW3T[HDIM * HDIM];
  __shared__ __align__(16) unsigned short sScr[4][4096];
  int t = threadIdx.x;
  for (int e = t; e < 2 * FDIM * HDIM; e += 256) {
    int i = e >> 6, j = e & 63;
    sW1T[swzi(j, i, 128)] = f2bf(W1[e]);
  }
  for (int e = t; e < HDIM * HDIM; e += 256) {
    int i = e >> 6, j = e & 63;
    sW2T[swzi(j, i, 64)] = f2bf(W2[e]);
    sW3T[swzi(j, i, 64)] = f2bf(W3[e]);
  }
  __syncthreads();

  int wv = t >> 6, lane = t & 63;
  int q = lane >> 4, cl = lane & 15;
  unsigned short* scr = &sScr[wv][0];
  unsigned int* scr32 = reinterpret_cast<unsigned int*>(scr);
  float bias1[4], bias2[4], bias3[4];
#pragma unroll
  for (int nt = 0; nt < 4; ++nt) {
    bias1[nt] = b1[nt * 16 + cl];
    bias2[nt] = b2[nt * 16 + cl];
    bias3[nt] = b3[nt * 16 + cl];
  }

  for (int vi = 0; vi < 4; ++vi) {
    int v = blockIdx.x * 16 + wv * 4 + vi;
    int b = v / V;
    int vloc = v - b * V;
    const float* xb = x + (size_t)b * V * FDIM;
    int hl = lane & 31;
    float2 c2 = *reinterpret_cast<const float2*>(xb + (size_t)vloc * FDIM + 2 * hl);
    int myidx = (lane < KNN) ? idx[(size_t)v * KNN + lane] : 0;

#pragma unroll 4
    for (int r = 0; r < 32; ++r) {
      int kk = (r < KNN) ? r : (KNN - 1);
      int nb = __shfl(myidx, kk);
      float2 n2 = *reinterpret_cast<const float2*>(xb + (size_t)nb * FDIM + 2 * hl);
      float e0, e1;
      if (lane < 32) { e0 = c2.x;        e1 = c2.y; }
      else           { e0 = c2.x - n2.x; e1 = c2.y - n2.y; }
      unsigned int pk = (unsigned int)f2bf(e0) | ((unsigned int)f2bf(e1) << 16);
      scr32[(r * 64 + lane) ^ ((r & 7) << 2)] = pk;
    }
    lds_fence();

    // ---- layer 1 ----
    s8v af[2][4];
#pragma unroll
    for (int mt = 0; mt < 2; ++mt)
#pragma unroll
      for (int ks = 0; ks < 4; ++ks)
        af[mt][ks] = *reinterpret_cast<const s8v*>(&scr[swzi(mt * 16 + cl, ks * 32 + q * 8, 128)]);
    f4v acc[2][4];
#pragma unroll
    for (int mt = 0; mt < 2; ++mt)
#pragma unroll
      for (int nt = 0; nt < 4; ++nt) {
        f4v a0 = {bias1[nt], bias1[nt], bias1[nt], bias1[nt]};
        acc[mt][nt] = a0;
      }
#pragma unroll
    for (int ks = 0; ks < 4; ++ks)
#pragma unroll
      for (int nt = 0; nt < 4; ++nt) {
        s8v wf = *reinterpret_cast<const s8v*>(&sW1T[swzi(nt * 16 + cl, ks * 32 + q * 8, 128)]);
        acc[0][nt] = __builtin_amdgcn_mfma_f32_16x16x32_bf16(af[0][ks], wf, acc[0][nt], 0, 0, 0);
        acc[1][nt] = __builtin_amdgcn_mfma_f32_16x16x32_bf16(af[1][ks], wf, acc[1][nt], 0, 0, 0);
      }
    lds_fence();
#pragma unroll
    for (int mt = 0; mt < 2; ++mt)
#pragma unroll
      for (int nt = 0; nt < 4; ++nt)
#pragma unroll
        for (int i = 0; i < 4; ++i) {
          float hv = fmaxf(acc[mt][nt][i], 0.0f);
          scr[swzi(mt * 16 + q * 4 + i, nt * 16 + cl, 64)] = f2bf(hv);
        }
    lds_fence();

    // ---- layer 2 ----
    s8v af2[2][2];
#pragma unroll
    for (int mt = 0; mt < 2; ++mt)
#pragma unroll
      for (int ks = 0; ks < 2; ++ks)
        af2[mt][ks] = *reinterpret_cast<const s8v*>(&scr[swzi(mt * 16 + cl, ks * 32 + q * 8, 64)]);
    f4v acc2[2][4];
#pragma unroll
    for (int mt = 0; mt < 2; ++mt)
#pragma unroll
      for (int nt = 0; nt < 4; ++nt) {
        f4v a0 = {bias2[nt], bias2[nt], bias2[nt], bias2[nt]};
        acc2[mt][nt] = a0;
      }
#pragma unroll
    for (int ks = 0; ks < 2; ++ks)
#pragma unroll
      for (int nt = 0; nt < 4; ++nt) {
        s8v wf = *reinterpret_cast<const s8v*>(&sW2T[swzi(nt * 16 + cl, ks * 32 + q * 8, 64)]);
        acc2[0][nt] = __builtin_amdgcn_mfma_f32_16x16x32_bf16(af2[0][ks], wf, acc2[0][nt], 0, 0, 0);
        acc2[1][nt] = __builtin_amdgcn_mfma_f32_16x16x32_bf16(af2[1][ks], wf, acc2[1][nt], 0, 0, 0);
      }
    lds_fence();
#pragma unroll
    for (int mt = 0; mt < 2; ++mt)
#pragma unroll
      for (int nt = 0; nt < 4; ++nt)
#pragma unroll
        for (int i = 0; i < 4; ++i) {
          float hv = fmaxf(acc2[mt][nt][i], 0.0f);
          scr[2048 + swzi(mt * 16 + q * 4 + i, nt * 16 + cl, 64)] = f2bf(hv);
        }
    lds_fence();

    // ---- layer 3 ----
    s8v af3[2][2];
#pragma unroll
    for (int mt = 0; mt < 2; ++mt)
#pragma unroll
      for (int ks = 0; ks < 2; ++ks)
        af3[mt][ks] = *reinterpret_cast<const s8v*>(&scr[2048 + swzi(mt * 16 + cl, ks * 32 + q * 8, 64)]);
    f4v acc3[2][4];
#pragma unroll
    for (int mt = 0; mt < 2; ++mt)
#pragma unroll
      for (int nt = 0; nt < 4; ++nt) {
        f4v a0 = {bias3[nt], bias3[nt], bias3[nt], bias3[nt]};
        acc3[mt][nt] = a0;
      }
#pragma unroll
    for (int ks = 0; ks < 2; ++ks)
#pragma unroll
      for (int nt = 0; nt < 4; ++nt) {
        s8v wf = *reinterpret_cast<const s8v*>(&sW3T[swzi(nt * 16 + cl, ks * 32 + q * 8, 64)]);
        acc3[0][nt] = __builtin_amdgcn_mfma_f32_16x16x32_bf16(af3[0][ks], wf, acc3[0][nt], 0, 0, 0);
        acc3[1][nt] = __builtin_amdgcn_mfma_f32_16x16x32_bf16(af3[1][ks], wf, acc3[1][nt], 0, 0, 0);
      }

    float m[4] = {0.0f, 0.0f, 0.0f, 0.0f};
#pragma unroll
    for (int nt = 0; nt < 4; ++nt)
#pragma unroll
      for (int mt = 0; mt < 2; ++mt)
#pragma unroll
        for (int i = 0; i < 4; ++i) m[nt] = fmaxf(m[nt], acc3[mt][nt][i]);
#pragma unroll
    for (int nt = 0; nt < 4; ++nt) {
      m[nt] = fmaxf(m[nt], __shfl_xor(m[nt], 16));
      m[nt] = fmaxf(m[nt], __shfl_xor(m[nt], 32));
    }
    float outv = (q == 0) ? m[0] : (q == 1) ? m[1] : (q == 2) ? m[2] : m[3];
    out[(size_t)v * HDIM + lane] = outv;
  }
}

extern "C" void kernel_launch(void* const* d_in, const int* in_sizes, int n_in,
                              void* d_out, int out_size, void* d_ws, size_t ws_size,
                              hipStream_t stream) {
  const float* x  = (const float*)d_in[0];
  const float* W1 = (const float*)d_in[2];
  const float* b1 = (const float*)d_in[3];
  const float* W2 = (const float*)d_in[4];
  const float* b2 = (const float*)d_in[5];
  const float* W3 = (const float*)d_in[6];
  const float* b3 = (const float*)d_in[7];
  float* out = (float*)d_out;
  int N = in_sizes[0] / FDIM;      // 32768
  int B = in_sizes[1] - 1;         // 16
  int V = N / B;                   // 2048

  char* ws = (char*)d_ws;
  float* sqbuf = (float*)ws;
  size_t off = (size_t)N * sizeof(float);
  int* idxbuf = (int*)(ws + off);
  off += (size_t)N * KNN * sizeof(int);
  off = (off + 255) & ~(size_t)255;
  float* Dbuf = (float*)(ws + off);
  size_t dcap = (ws_size > off) ? (ws_size - off) : 0;
  long long capRows = (long long)(dcap / ((size_t)V * sizeof(float)));
  capRows &= ~63LL;
  if (capRows > N) capRows = N;
  if (capRows < 64) capRows = 64;  // requires ws_size >= ~4.7 MB

  sq_kernel<<<N / 4, 256, 0, stream>>>(x, sqbuf);
  for (int R0 = 0; R0 < N; R0 += (int)capRows) {
    int nr = N - R0;
    if (nr > capRows) nr = (int)capRows;
    dim3 g(V / 64, nr / 64);
    dist_kernel<<<g, 256, 0, stream>>>(x, sqbuf, Dbuf, R0, V);
    topk_kernel<<<nr / 4, 256, 0, stream>>>(Dbuf, idxbuf, R0, nr, V);
  }
  mlp_kernel<<<N / 16, 256, 0, stream>>>(x, idxbuf, W1, b1, W2, b2, W3, b3, out, V);
}

// Round 3
// 238.454 us; speedup vs baseline: 2.8091x; 1.5501x over previous
//
#include <hip/hip_runtime.h>

#define KNN 30
#define FDIM 64
#define HDIM 64

typedef short s8v __attribute__((ext_vector_type(8)));   // 8 bf16 bit-patterns (4 VGPR)
typedef float f4v __attribute__((ext_vector_type(4)));   // MFMA accumulator

// round-to-nearest-even f32 -> bf16 bits
static __device__ __forceinline__ unsigned short f2bf(float f) {
  unsigned int u = __builtin_bit_cast(unsigned int, f);
  u += 0x7fffu + ((u >> 16) & 1u);
  return (unsigned short)(u >> 16);
}
static __device__ __forceinline__ float bf2f(unsigned short h) {
  unsigned int u = ((unsigned int)h) << 16;
  return __builtin_bit_cast(float, u);
}

// f32 bits -> order-preserving u32 (asc float order == asc uint order)
static __device__ __forceinline__ unsigned int f2sort(float f) {
  unsigned int u = __builtin_bit_cast(unsigned int, f);
  unsigned int m = (unsigned int)(((int)u) >> 31) | 0x80000000u;
  return u ^ m;
}

// XOR swizzle (ushort-index space): byte ^= (row&7)<<4  <=>  idx ^= (row&7)<<3
static __device__ __forceinline__ int swzi(int row, int col, int roww) {
  return (row * roww + col) ^ ((row & 7) << 3);
}

static __device__ __forceinline__ void lds_fence() {
  asm volatile("s_waitcnt lgkmcnt(0)" ::: "memory");
  __builtin_amdgcn_sched_barrier(0);
}

// ---------------- sq[i] = |x_i|^2 ----------------
__global__ __launch_bounds__(256) void sq_kernel(const float* __restrict__ x,
                                                 float* __restrict__ sq) {
  int lane = threadIdx.x & 63;
  int row = blockIdx.x * 4 + (threadIdx.x >> 6);
  float v = x[(size_t)row * FDIM + lane];
  float s = v * v;
#pragma unroll
  for (int off = 32; off; off >>= 1) s += __shfl_xor(s, off);
  if (lane == 0) sq[row] = s;
}

// ---------------- U/P precompute ----------------
// U[v][h] = x_v @ (W1a+W1b)[:,h] + b1[h]   (f32)
// P[v][h] = x_v @ W1b[:,h]                 (bf16)
// h1_pre(edge v,k) = U[v] - P[idx[v,k]]  (layer-1 algebraic elimination)
__global__ __launch_bounds__(256) void uP_kernel(const float* __restrict__ x,
                                                 const float* __restrict__ W1,
                                                 const float* __restrict__ b1,
                                                 float* __restrict__ U,
                                                 unsigned short* __restrict__ P) {
  __shared__ __align__(16) unsigned short sWT[128 * 64];  // rows: h'<64 = (W1a+W1b)^T, h'>=64 = W1b^T
  int t = threadIdx.x;
  for (int e = t; e < 64 * 64; e += 256) {
    int f = e >> 6, h = e & 63;
    float wa = W1[f * 64 + h];
    float wb = W1[(64 + f) * 64 + h];
    sWT[swzi(h, f, 64)] = f2bf(wa + wb);
    sWT[swzi(64 + h, f, 64)] = f2bf(wb);
  }
  __syncthreads();
  int wv = t >> 6, lane = t & 63;
  int q = lane >> 4, cl = lane & 15;
  int base = blockIdx.x * 128 + wv * 32;

  // A fragments: row = base + mt*16 + cl, k = ks*32 + q*8 + j
  s8v af[2][2];
#pragma unroll
  for (int mt = 0; mt < 2; ++mt)
#pragma unroll
    for (int ks = 0; ks < 2; ++ks) {
      const float* px = x + (size_t)(base + mt * 16 + cl) * FDIM + ks * 32 + q * 8;
      float4 a = *reinterpret_cast<const float4*>(px);
      float4 b = *reinterpret_cast<const float4*>(px + 4);
      s8v v;
      v[0] = (short)f2bf(a.x); v[1] = (short)f2bf(a.y);
      v[2] = (short)f2bf(a.z); v[3] = (short)f2bf(a.w);
      v[4] = (short)f2bf(b.x); v[5] = (short)f2bf(b.y);
      v[6] = (short)f2bf(b.z); v[7] = (short)f2bf(b.w);
      af[mt][ks] = v;
    }
  f4v acc[2][8];
#pragma unroll
  for (int nt = 0; nt < 8; ++nt) {
    float bb = (nt < 4) ? b1[nt * 16 + cl] : 0.0f;
    f4v a0 = {bb, bb, bb, bb};
    acc[0][nt] = a0;
    acc[1][nt] = a0;
  }
#pragma unroll
  for (int ks = 0; ks < 2; ++ks)
#pragma unroll
    for (int nt = 0; nt < 8; ++nt) {
      s8v wf = *reinterpret_cast<const s8v*>(&sWT[swzi(nt * 16 + cl, ks * 32 + q * 8, 64)]);
      acc[0][nt] = __builtin_amdgcn_mfma_f32_16x16x32_bf16(af[0][ks], wf, acc[0][nt], 0, 0, 0);
      acc[1][nt] = __builtin_amdgcn_mfma_f32_16x16x32_bf16(af[1][ks], wf, acc[1][nt], 0, 0, 0);
    }
#pragma unroll
  for (int mt = 0; mt < 2; ++mt)
#pragma unroll
    for (int nt = 0; nt < 8; ++nt)
#pragma unroll
      for (int i = 0; i < 4; ++i) {
        int row = base + mt * 16 + q * 4 + i;
        if (nt < 4) U[(size_t)row * 64 + nt * 16 + cl] = acc[mt][nt][i];
        else        P[(size_t)row * 64 + (nt - 4) * 16 + cl] = f2bf(acc[mt][nt][i]);
      }
}

// ---------------- distance tiles: D[row][w] = sq[w] - 2*dot(x_v, x_w) ----------------
__global__ __launch_bounds__(256) void dist_kernel(const float* __restrict__ x,
                                                   const float* __restrict__ sq,
                                                   float* __restrict__ D,
                                                   int R0, int V) {
  __shared__ float XvT[FDIM][68];
  __shared__ float XwT[FDIM][68];
  int R = R0 + blockIdx.y * 64;
  int b = R / V;
  int v0 = R - b * V;
  int w0 = blockIdx.x * 64;
  const float* xb = x + (size_t)b * V * FDIM;
  int t = threadIdx.x;
  {
    int r = t >> 2;
    int f0 = (t & 3) * 16;
    const float* pv = xb + (size_t)(v0 + r) * FDIM + f0;
    const float* pw = xb + (size_t)(w0 + r) * FDIM + f0;
#pragma unroll
    for (int i = 0; i < 4; ++i) {
      float4 a = *reinterpret_cast<const float4*>(pv + i * 4);
      float4 c = *reinterpret_cast<const float4*>(pw + i * 4);
      int f = f0 + i * 4;
      XvT[f + 0][r] = a.x; XvT[f + 1][r] = a.y; XvT[f + 2][r] = a.z; XvT[f + 3][r] = a.w;
      XwT[f + 0][r] = c.x; XwT[f + 1][r] = c.y; XwT[f + 2][r] = c.z; XwT[f + 3][r] = c.w;
    }
  }
  __syncthreads();
  int tx = t & 15, ty = t >> 4;
  float acc[4][4] = {};
#pragma unroll 8
  for (int k = 0; k < FDIM; ++k) {
    float4 av = *reinterpret_cast<const float4*>(&XvT[k][ty * 4]);
    float4 bv = *reinterpret_cast<const float4*>(&XwT[k][tx * 4]);
    float aa[4] = {av.x, av.y, av.z, av.w};
    float bb[4] = {bv.x, bv.y, bv.z, bv.w};
#pragma unroll
    for (int i = 0; i < 4; ++i)
#pragma unroll
      for (int j = 0; j < 4; ++j) acc[i][j] = fmaf(aa[i], bb[j], acc[i][j]);
  }
  int wbase = w0 + tx * 4;
  float sw[4];
#pragma unroll
  for (int j = 0; j < 4; ++j) sw[j] = sq[(size_t)b * V + wbase + j];
  size_t drow0 = (size_t)(blockIdx.y * 64 + ty * 4);
#pragma unroll
  for (int i = 0; i < 4; ++i) {
    float4 o;
    o.x = sw[0] - 2.0f * acc[i][0];
    o.y = sw[1] - 2.0f * acc[i][1];
    o.z = sw[2] - 2.0f * acc[i][2];
    o.w = sw[3] - 2.0f * acc[i][3];
    *reinterpret_cast<float4*>(&D[(drow0 + i) * (size_t)V + wbase]) = o;
  }
}

// ---------------- top-30 smallest per row via threshold+compact+bitonic ----------------
__global__ __launch_bounds__(256) void topk_kernel(const float* __restrict__ D,
                                                   int* __restrict__ idxout,
                                                   int R0, int nrows, int V) {
  __shared__ unsigned long long cand[4][64];
  int wave = threadIdx.x >> 6, lane = threadIdx.x & 63;
  int rowL = blockIdx.x * 4 + wave;
  if (rowL >= nrows) return;
  int R = R0 + rowL;
  const float* row = D + (size_t)rowL * (size_t)V;

  unsigned int sv[32];
  int wb = lane * 4;
#pragma unroll
  for (int s = 0; s < 8; ++s) {
    float4 f = reinterpret_cast<const float4*>(row)[s * 64 + lane];
    sv[s * 4 + 0] = f2sort(f.x);
    sv[s * 4 + 1] = f2sort(f.y);
    sv[s * 4 + 2] = f2sort(f.z);
    sv[s * 4 + 3] = f2sort(f.w);
  }
  unsigned int mn = sv[0];
#pragma unroll
  for (int r = 1; r < 32; ++r) mn = min(mn, sv[r]);

  unsigned int srt = mn;
#pragma unroll
  for (int k = 2; k <= 64; k <<= 1) {
#pragma unroll
    for (int j = k >> 1; j > 0; j >>= 1) {
      unsigned int o = __shfl_xor(srt, j);
      bool keep_min = ((lane & k) == 0) == ((lane & j) == 0);
      bool less = srt < o;
      srt = (keep_min == less) ? srt : o;
    }
  }
  unsigned int tau = __shfl(srt, 30);

  int base = 0;
#pragma unroll
  for (int r = 0; r < 32; ++r) {
    bool pred = sv[r] <= tau;
    unsigned long long m = __ballot(pred);
    unsigned int off = __builtin_amdgcn_mbcnt_lo((unsigned int)m, 0u);
    off = __builtin_amdgcn_mbcnt_hi((unsigned int)(m >> 32), off);
    int slot = base + (int)off;
    if (pred && slot < 64) {
      unsigned int w = (unsigned int)((r >> 2) * 256 + wb + (r & 3));
      cand[wave][slot] = ((unsigned long long)sv[r] << 32) | w;
    }
    base += (int)__popcll(m);
  }

  if (base <= 64) {
    lds_fence();
    unsigned long long key = cand[wave][lane];
    if (lane >= base) key = ~0ULL;
#pragma unroll
    for (int k = 2; k <= 64; k <<= 1) {
#pragma unroll
      for (int j = k >> 1; j > 0; j >>= 1) {
        unsigned long long o = __shfl_xor(key, j);
        bool keep_min = ((lane & k) == 0) == ((lane & j) == 0);
        bool less = key < o;
        key = (keep_min == less) ? key : o;
      }
    }
    if (lane >= 1 && lane <= KNN)
      idxout[(size_t)R * KNN + (lane - 1)] = (int)(unsigned int)key;
  } else {
    unsigned int removed = 0;
    for (int it = 0; it < KNN + 1; ++it) {
      unsigned long long m = ~0ULL;
#pragma unroll
      for (int r = 0; r < 32; ++r) {
        unsigned long long key =
            ((unsigned long long)sv[r] << 32) | (unsigned int)((r >> 2) * 256 + wb + (r & 3));
        bool alive = ((removed >> r) & 1u) == 0u;
        if (alive && key < m) m = key;
      }
      unsigned long long g = m;
#pragma unroll
      for (int off = 32; off; off >>= 1) {
        unsigned long long o = __shfl_xor(g, off);
        g = (o < g) ? o : g;
      }
      if (it > 0 && lane == 0) idxout[(size_t)R * KNN + (it - 1)] = (int)(unsigned int)g;
#pragma unroll
      for (int r = 0; r < 32; ++r) {
        unsigned long long key =
            ((unsigned long long)sv[r] << 32) | (unsigned int)((r >> 2) * 256 + wb + (r & 3));
        if (key == g) removed |= (1u << r);
      }
    }
  }
}

// ---------------- fused layers 2,3 + max aggregation ----------------
// H1[r] = relu(U[v] - P[nb_r]) built directly from precomputed U/P (layer 1 eliminated).
// H2 stored nt-interleaved (storage col s = 4*cl + nt; perm s(h) = (h&15)*4 + (h>>4));
// W3 staged with the same perm on its input dim so the MFMA dot is unchanged.
__global__ __launch_bounds__(256) void mlp_kernel(const float* __restrict__ U,
                                                  const unsigned short* __restrict__ P,
                                                  const int* __restrict__ idx,
                                                  const float* __restrict__ W2,
                                                  const float* __restrict__ b2,
                                                  const float* __restrict__ W3,
                                                  const float* __restrict__ b3,
                                                  float* __restrict__ out, int V) {
  __shared__ __align__(16) unsigned short sW2T[HDIM * HDIM];  // [n][k] natural
  __shared__ __align__(16) unsigned short sW3T[HDIM * HDIM];  // [n][s(k)] permuted
  __shared__ __align__(16) unsigned short sScr[4][2048];      // 4KB/wave: H tile [32][64]
  int t = threadIdx.x;
  for (int e = t; e < HDIM * HDIM; e += 256) {
    int i = e >> 6, j = e & 63;  // W[i][j]
    sW2T[swzi(j, i, 64)] = f2bf(W2[e]);
    int s = (i & 15) * 4 + (i >> 4);
    sW3T[swzi(j, s, 64)] = f2bf(W3[e]);
  }
  __syncthreads();

  int wv = t >> 6, lane = t & 63;
  int q = lane >> 4, cl = lane & 15;
  int g = lane >> 3, sub = lane & 7;
  unsigned short* scr = &sScr[wv][0];
  float bias2[4], bias3[4];
#pragma unroll
  for (int nt = 0; nt < 4; ++nt) {
    bias2[nt] = b2[nt * 16 + cl];
    bias3[nt] = b3[nt * 16 + cl];
  }

  for (int vi = 0; vi < 4; ++vi) {
    int v = blockIdx.x * 16 + wv * 4 + vi;
    int b = v / V;
    size_t bbase = (size_t)b * V;
    int myidx = (lane < KNN) ? idx[(size_t)v * KNN + lane] : 0;
    // per-lane slice of U[v]: cols sub*8 .. +8
    const float* up = U + (size_t)v * 64 + sub * 8;
    float4 u0 = *reinterpret_cast<const float4*>(up);
    float4 u1 = *reinterpret_cast<const float4*>(up + 4);
    float uu[8] = {u0.x, u0.y, u0.z, u0.w, u1.x, u1.y, u1.z, u1.w};

    // gather + H1 build: iteration it covers rows it*8+g, lane chunk sub*8
#pragma unroll
    for (int it = 0; it < 4; ++it) {
      int r = it * 8 + g;
      int kk = (r < KNN) ? r : (KNN - 1);
      int nb = __shfl(myidx, kk);
      const unsigned short* pp = P + (bbase + (unsigned int)nb) * 64 + sub * 8;
      s8v p8 = *reinterpret_cast<const s8v*>(pp);
      s8v hv;
#pragma unroll
      for (int j = 0; j < 8; ++j) {
        float f = uu[j] - bf2f((unsigned short)p8[j]);
        hv[j] = (short)f2bf(fmaxf(f, 0.0f));
      }
      *reinterpret_cast<s8v*>(&scr[swzi(r, sub * 8, 64)]) = hv;
    }
    lds_fence();

    // ---- layer 2: [32x64] @ [64x64] ----
    s8v af2[2][2];
#pragma unroll
    for (int mt = 0; mt < 2; ++mt)
#pragma unroll
      for (int ks = 0; ks < 2; ++ks)
        af2[mt][ks] = *reinterpret_cast<const s8v*>(&scr[swzi(mt * 16 + cl, ks * 32 + q * 8, 64)]);
    f4v acc2[2][4];
#pragma unroll
    for (int mt = 0; mt < 2; ++mt)
#pragma unroll
      for (int nt = 0; nt < 4; ++nt) {
        f4v a0 = {bias2[nt], bias2[nt], bias2[nt], bias2[nt]};
        acc2[mt][nt] = a0;
      }
#pragma unroll
    for (int ks = 0; ks < 2; ++ks)
#pragma unroll
      for (int nt = 0; nt < 4; ++nt) {
        s8v wf = *reinterpret_cast<const s8v*>(&sW2T[swzi(nt * 16 + cl, ks * 32 + q * 8, 64)]);
        acc2[0][nt] = __builtin_amdgcn_mfma_f32_16x16x32_bf16(af2[0][ks], wf, acc2[0][nt], 0, 0, 0);
        acc2[1][nt] = __builtin_amdgcn_mfma_f32_16x16x32_bf16(af2[1][ks], wf, acc2[1][nt], 0, 0, 0);
      }
    lds_fence();
    // relu -> H2, nt-interleaved packed b64 stores (overwrites H1 region)
#pragma unroll
    for (int mt = 0; mt < 2; ++mt)
#pragma unroll
      for (int i = 0; i < 4; ++i) {
        int m = mt * 16 + q * 4 + i;
        unsigned long long pk = 0;
#pragma unroll
        for (int nt = 0; nt < 4; ++nt) {
          unsigned long long hb = f2bf(fmaxf(acc2[mt][nt][i], 0.0f));
          pk |= hb << (16 * nt);
        }
        *reinterpret_cast<unsigned long long*>(&scr[swzi(m, cl * 4, 64)]) = pk;
      }
    lds_fence();

    // ---- layer 3: [32x64] @ [64x64] (s-permuted k-dim) ----
    s8v af3[2][2];
#pragma unroll
    for (int mt = 0; mt < 2; ++mt)
#pragma unroll
      for (int ks = 0; ks < 2; ++ks)
        af3[mt][ks] = *reinterpret_cast<const s8v*>(&scr[swzi(mt * 16 + cl, ks * 32 + q * 8, 64)]);
    f4v acc3[2][4];
#pragma unroll
    for (int mt = 0; mt < 2; ++mt)
#pragma unroll
      for (int nt = 0; nt < 4; ++nt) {
        f4v a0 = {bias3[nt], bias3[nt], bias3[nt], bias3[nt]};
        acc3[mt][nt] = a0;
      }
#pragma unroll
    for (int ks = 0; ks < 2; ++ks)
#pragma unroll
      for (int nt = 0; nt < 4; ++nt) {
        s8v wf = *reinterpret_cast<const s8v*>(&sW3T[swzi(nt * 16 + cl, ks * 32 + q * 8, 64)]);
        acc3[0][nt] = __builtin_amdgcn_mfma_f32_16x16x32_bf16(af3[0][ks], wf, acc3[0][nt], 0, 0, 0);
        acc3[1][nt] = __builtin_amdgcn_mfma_f32_16x16x32_bf16(af3[1][ks], wf, acc3[1][nt], 0, 0, 0);
      }

    float m[4] = {0.0f, 0.0f, 0.0f, 0.0f};
#pragma unroll
    for (int nt = 0; nt < 4; ++nt)
#pragma unroll
      for (int mt = 0; mt < 2; ++mt)
#pragma unroll
        for (int i = 0; i < 4; ++i) m[nt] = fmaxf(m[nt], acc3[mt][nt][i]);
#pragma unroll
    for (int nt = 0; nt < 4; ++nt) {
      m[nt] = fmaxf(m[nt], __shfl_xor(m[nt], 16));
      m[nt] = fmaxf(m[nt], __shfl_xor(m[nt], 32));
    }
    float outv = (q == 0) ? m[0] : (q == 1) ? m[1] : (q == 2) ? m[2] : m[3];
    out[(size_t)v * HDIM + lane] = outv;
  }
}

extern "C" void kernel_launch(void* const* d_in, const int* in_sizes, int n_in,
                              void* d_out, int out_size, void* d_ws, size_t ws_size,
                              hipStream_t stream) {
  const float* x  = (const float*)d_in[0];
  const float* W1 = (const float*)d_in[2];
  const float* b1 = (const float*)d_in[3];
  const float* W2 = (const float*)d_in[4];
  const float* b2 = (const float*)d_in[5];
  const float* W3 = (const float*)d_in[6];
  const float* b3 = (const float*)d_in[7];
  float* out = (float*)d_out;
  int N = in_sizes[0] / FDIM;      // 32768
  int B = in_sizes[1] - 1;         // 16
  int V = N / B;                   // 2048

  char* ws = (char*)d_ws;
  float* sqbuf = (float*)ws;
  size_t off = (size_t)N * sizeof(float);
  int* idxbuf = (int*)(ws + off);
  off += (size_t)N * KNN * sizeof(int);
  off = (off + 255) & ~(size_t)255;
  float* Ubuf = (float*)(ws + off);
  off += (size_t)N * 64 * sizeof(float);
  unsigned short* Pbuf = (unsigned short*)(ws + off);
  off += (size_t)N * 64 * sizeof(unsigned short);
  off = (off + 255) & ~(size_t)255;
  float* Dbuf = (float*)(ws + off);
  size_t dcap = (ws_size > off) ? (ws_size - off) : 0;
  long long capRows = (long long)(dcap / ((size_t)V * sizeof(float)));
  capRows &= ~63LL;
  if (capRows > N) capRows = N;
  if (capRows < 64) capRows = 64;  // requires sufficient ws_size

  sq_kernel<<<N / 4, 256, 0, stream>>>(x, sqbuf);
  uP_kernel<<<N / 128, 256, 0, stream>>>(x, W1, b1, Ubuf, Pbuf);
  for (int R0 = 0; R0 < N; R0 += (int)capRows) {
    int nr = N - R0;
    if (nr > capRows) nr = (int)capRows;
    dim3 g(V / 64, nr / 64);
    dist_kernel<<<g, 256, 0, stream>>>(x, sqbuf, Dbuf, R0, V);
    topk_kernel<<<nr / 4, 256, 0, stream>>>(Dbuf, idxbuf, R0, nr, V);
  }
  mlp_kernel<<<N / 16, 256, 0, stream>>>(Ubuf, Pbuf, idxbuf, W2, b2, W3, b3, out, V);
}

// Round 4
// 221.758 us; speedup vs baseline: 3.0206x; 1.0753x over previous
//
#include <hip/hip_runtime.h>

#define KNN 30
#define FDIM 64
#define HDIM 64

typedef short s8v __attribute__((ext_vector_type(8)));   // 8 bf16 bit-patterns (4 VGPR)
typedef float f4v __attribute__((ext_vector_type(4)));   // MFMA accumulator
typedef unsigned long long u64;

// round-to-nearest-even f32 -> bf16 bits
static __device__ __forceinline__ unsigned short f2bf(float f) {
  unsigned int u = __builtin_bit_cast(unsigned int, f);
  u += 0x7fffu + ((u >> 16) & 1u);
  return (unsigned short)(u >> 16);
}
static __device__ __forceinline__ float bf2f(unsigned short h) {
  unsigned int u = ((unsigned int)h) << 16;
  return __builtin_bit_cast(float, u);
}

// f32 bits -> order-preserving u32 (asc float order == asc uint order)
static __device__ __forceinline__ unsigned int f2sort(float f) {
  unsigned int u = __builtin_bit_cast(unsigned int, f);
  unsigned int m = (unsigned int)(((int)u) >> 31) | 0x80000000u;
  return u ^ m;
}

// XOR swizzle (ushort-index space): byte ^= (row&7)<<4  <=>  idx ^= (row&7)<<3
static __device__ __forceinline__ int swzi(int row, int col, int roww) {
  return (row * roww + col) ^ ((row & 7) << 3);
}

static __device__ __forceinline__ void lds_fence() {
  asm volatile("s_waitcnt lgkmcnt(0)" ::: "memory");
  __builtin_amdgcn_sched_barrier(0);
}

// ---------------- sq[i] = |x_i|^2 ----------------
__global__ __launch_bounds__(256) void sq_kernel(const float* __restrict__ x,
                                                 float* __restrict__ sq) {
  int lane = threadIdx.x & 63;
  int row = blockIdx.x * 4 + (threadIdx.x >> 6);
  float v = x[(size_t)row * FDIM + lane];
  float s = v * v;
#pragma unroll
  for (int off = 32; off; off >>= 1) s += __shfl_xor(s, off);
  if (lane == 0) sq[row] = s;
}

// ---------------- U/P precompute (layer-1 algebraic elimination) ----------------
__global__ __launch_bounds__(256) void uP_kernel(const float* __restrict__ x,
                                                 const float* __restrict__ W1,
                                                 const float* __restrict__ b1,
                                                 float* __restrict__ U,
                                                 unsigned short* __restrict__ P) {
  __shared__ __align__(16) unsigned short sWT[128 * 64];
  int t = threadIdx.x;
  for (int e = t; e < 64 * 64; e += 256) {
    int f = e >> 6, h = e & 63;
    float wa = W1[f * 64 + h];
    float wb = W1[(64 + f) * 64 + h];
    sWT[swzi(h, f, 64)] = f2bf(wa + wb);
    sWT[swzi(64 + h, f, 64)] = f2bf(wb);
  }
  __syncthreads();
  int wv = t >> 6, lane = t & 63;
  int q = lane >> 4, cl = lane & 15;
  int base = blockIdx.x * 128 + wv * 32;

  s8v af[2][2];
#pragma unroll
  for (int mt = 0; mt < 2; ++mt)
#pragma unroll
    for (int ks = 0; ks < 2; ++ks) {
      const float* px = x + (size_t)(base + mt * 16 + cl) * FDIM + ks * 32 + q * 8;
      float4 a = *reinterpret_cast<const float4*>(px);
      float4 b = *reinterpret_cast<const float4*>(px + 4);
      s8v v;
      v[0] = (short)f2bf(a.x); v[1] = (short)f2bf(a.y);
      v[2] = (short)f2bf(a.z); v[3] = (short)f2bf(a.w);
      v[4] = (short)f2bf(b.x); v[5] = (short)f2bf(b.y);
      v[6] = (short)f2bf(b.z); v[7] = (short)f2bf(b.w);
      af[mt][ks] = v;
    }
  f4v acc[2][8];
#pragma unroll
  for (int nt = 0; nt < 8; ++nt) {
    float bb = (nt < 4) ? b1[nt * 16 + cl] : 0.0f;
    f4v a0 = {bb, bb, bb, bb};
    acc[0][nt] = a0;
    acc[1][nt] = a0;
  }
#pragma unroll
  for (int ks = 0; ks < 2; ++ks)
#pragma unroll
    for (int nt = 0; nt < 8; ++nt) {
      s8v wf = *reinterpret_cast<const s8v*>(&sWT[swzi(nt * 16 + cl, ks * 32 + q * 8, 64)]);
      acc[0][nt] = __builtin_amdgcn_mfma_f32_16x16x32_bf16(af[0][ks], wf, acc[0][nt], 0, 0, 0);
      acc[1][nt] = __builtin_amdgcn_mfma_f32_16x16x32_bf16(af[1][ks], wf, acc[1][nt], 0, 0, 0);
    }
#pragma unroll
  for (int mt = 0; mt < 2; ++mt)
#pragma unroll
    for (int nt = 0; nt < 8; ++nt)
#pragma unroll
      for (int i = 0; i < 4; ++i) {
        int row = base + mt * 16 + q * 4 + i;
        if (nt < 4) U[(size_t)row * 64 + nt * 16 + cl] = acc[mt][nt][i];
        else        P[(size_t)row * 64 + (nt - 4) * 16 + cl] = f2bf(acc[mt][nt][i]);
      }
}

// ---------------- dist16: bf16-MFMA Gram -> u16 fixed-point keys ----------------
// key = clamp(round((sq[w] - 2*dot_bf16(x_v,x_w) + 256) * 64), 0, 65535)
// 128x128 tile per block; A/B tiles + key tile share one 32KB LDS buffer.
__global__ __launch_bounds__(256) void dist16_kernel(const float* __restrict__ x,
                                                     const float* __restrict__ sq,
                                                     unsigned short* __restrict__ D16,
                                                     int R0, int V) {
  __shared__ __align__(16) unsigned short sAB[16384];  // A[0,8192) B[8192,16384); then keys
  int t = threadIdx.x;
  int R = R0 + blockIdx.y * 128;
  int b = R / V;
  int v0 = R - b * V;
  int w0 = blockIdx.x * 128;
  const float* xb = x + (size_t)b * V * FDIM;
  {
    int r = t >> 1, half = t & 1;
    const float* pv = xb + (size_t)(v0 + r) * FDIM + half * 32;
    const float* pw = xb + (size_t)(w0 + r) * FDIM + half * 32;
#pragma unroll
    for (int j = 0; j < 4; ++j) {
      float4 a0 = *reinterpret_cast<const float4*>(pv + j * 8);
      float4 a1 = *reinterpret_cast<const float4*>(pv + j * 8 + 4);
      float4 c0 = *reinterpret_cast<const float4*>(pw + j * 8);
      float4 c1 = *reinterpret_cast<const float4*>(pw + j * 8 + 4);
      s8v pa, pc;
      pa[0] = (short)f2bf(a0.x); pa[1] = (short)f2bf(a0.y);
      pa[2] = (short)f2bf(a0.z); pa[3] = (short)f2bf(a0.w);
      pa[4] = (short)f2bf(a1.x); pa[5] = (short)f2bf(a1.y);
      pa[6] = (short)f2bf(a1.z); pa[7] = (short)f2bf(a1.w);
      pc[0] = (short)f2bf(c0.x); pc[1] = (short)f2bf(c0.y);
      pc[2] = (short)f2bf(c0.z); pc[3] = (short)f2bf(c0.w);
      pc[4] = (short)f2bf(c1.x); pc[5] = (short)f2bf(c1.y);
      pc[6] = (short)f2bf(c1.z); pc[7] = (short)f2bf(c1.w);
      *reinterpret_cast<s8v*>(&sAB[swzi(r, half * 32 + j * 8, 64)]) = pa;
      *reinterpret_cast<s8v*>(&sAB[8192 + swzi(r, half * 32 + j * 8, 64)]) = pc;
    }
  }
  __syncthreads();
  int wv = t >> 6, lane = t & 63;
  int q = lane >> 4, cl = lane & 15;
  int mq = wv >> 1, nq = wv & 1;  // 64x64 quadrant per wave
  s8v af[4][2], bfr[4][2];
#pragma unroll
  for (int mt = 0; mt < 4; ++mt)
#pragma unroll
    for (int ks = 0; ks < 2; ++ks) {
      af[mt][ks]  = *reinterpret_cast<const s8v*>(&sAB[swzi(mq * 64 + mt * 16 + cl, ks * 32 + q * 8, 64)]);
      bfr[mt][ks] = *reinterpret_cast<const s8v*>(&sAB[8192 + swzi(nq * 64 + mt * 16 + cl, ks * 32 + q * 8, 64)]);
    }
  f4v acc[4][4];
#pragma unroll
  for (int mt = 0; mt < 4; ++mt)
#pragma unroll
    for (int nt = 0; nt < 4; ++nt) {
      f4v z = {0.0f, 0.0f, 0.0f, 0.0f};
      acc[mt][nt] = z;
    }
#pragma unroll
  for (int ks = 0; ks < 2; ++ks)
#pragma unroll
    for (int mt = 0; mt < 4; ++mt)
#pragma unroll
      for (int nt = 0; nt < 4; ++nt)
        acc[mt][nt] = __builtin_amdgcn_mfma_f32_16x16x32_bf16(af[mt][ks], bfr[nt][ks], acc[mt][nt], 0, 0, 0);
  float sql[4];
#pragma unroll
  for (int nt = 0; nt < 4; ++nt) sql[nt] = sq[(size_t)b * V + w0 + nq * 64 + nt * 16 + cl];
  __syncthreads();  // all frag reads done; reuse sAB as key tile [128][128]
#pragma unroll
  for (int mt = 0; mt < 4; ++mt)
#pragma unroll
    for (int nt = 0; nt < 4; ++nt)
#pragma unroll
      for (int i = 0; i < 4; ++i) {
        int rl = mq * 64 + mt * 16 + q * 4 + i;
        int cll = nq * 64 + nt * 16 + cl;
        // 64*(sq_w - 2*dot + 256)
        float dk = fmaf(-128.0f, acc[mt][nt][i], fmaf(64.0f, sql[nt], 16384.0f));
        int ki = (int)(dk + 0.5f);
        ki = ki < 0 ? 0 : (ki > 65535 ? 65535 : ki);
        sAB[(rl * 128 + cll) ^ ((rl & 7) << 3)] = (unsigned short)ki;
      }
  __syncthreads();
  {
    int r = t >> 1, half = t & 1;
    size_t gbase = (size_t)(blockIdx.y * 128 + r) * (size_t)V + w0 + half * 64;
#pragma unroll
    for (int j = 0; j < 8; ++j) {
      s8v kk = *reinterpret_cast<const s8v*>(&sAB[(r * 128 + half * 64 + j * 8) ^ ((r & 7) << 3)]);
      *reinterpret_cast<s8v*>(&D16[gbase + j * 8]) = kk;
    }
  }
}

// ---------------- topk16: approx-select (u16 keys + margin) + exact fp32 rescan ----------------
// Margin derivation: |d_bf16 - d_fp32| <= E (=0.5, ~10 sigma). Exact-top-31 subset of
// {approx_key <= tau_key + 128E+2 = 66} where tau = rank-30 of 64 per-lane minima.
__global__ __launch_bounds__(256) void topk16_kernel(const unsigned short* __restrict__ D16,
                                                     const float* __restrict__ x,
                                                     const float* __restrict__ sq,
                                                     int* __restrict__ idxout,
                                                     int R0, int nrows, int V) {
  __shared__ unsigned int pool[4][128];
  __shared__ u64 pool2[4][128];
  __shared__ float sXv[4][64];
  int wave = threadIdx.x >> 6, lane = threadIdx.x & 63;
  int rowL = blockIdx.x * 4 + wave;
  if (rowL >= nrows) return;
  int R = R0 + rowL;
  int b = R / V;
  size_t bbase = (size_t)b * V;
  const unsigned short* row16 = D16 + (size_t)rowL * (size_t)V;

  // 32 combined keys per lane: (key16<<16)|w, w = s*512 + lane*8 + j
  unsigned int kv[32];
#pragma unroll
  for (int s = 0; s < 4; ++s) {
    s8v raw = *reinterpret_cast<const s8v*>(row16 + s * 512 + lane * 8);
#pragma unroll
    for (int j = 0; j < 8; ++j)
      kv[s * 8 + j] = ((unsigned int)(unsigned short)raw[j] << 16) | (unsigned int)(s * 512 + lane * 8 + j);
  }
  unsigned int mn = kv[0];
#pragma unroll
  for (int r = 1; r < 32; ++r) mn = min(mn, kv[r]);

  // bitonic-64 of lane minima -> tau (rank 30) bounds true rank-31 from above
  unsigned int srt = mn;
#pragma unroll
  for (int k = 2; k <= 64; k <<= 1) {
#pragma unroll
    for (int j = k >> 1; j > 0; j >>= 1) {
      unsigned int o = __shfl_xor(srt, j);
      bool keep_min = ((lane & k) == 0) == ((lane & j) == 0);
      bool less = srt < o;
      srt = (keep_min == less) ? srt : o;
    }
  }
  unsigned int tauk = (__shfl(srt, 30) >> 16) + 66;

  // compact candidates (key16 <= tauk) into pool
  int base = 0;
#pragma unroll
  for (int r = 0; r < 32; ++r) {
    bool pred = (kv[r] >> 16) <= tauk;
    u64 m = __ballot(pred);
    unsigned int off = __builtin_amdgcn_mbcnt_lo((unsigned int)m, 0u);
    off = __builtin_amdgcn_mbcnt_hi((unsigned int)(m >> 32), off);
    int slot = base + (int)off;
    if (pred && slot < 128) pool[wave][slot] = kv[r];
    base += (int)__popcll(m);
  }

  if (base <= 128) {
    lds_fence();
    // exact fp32 rescan: 8-lane groups, group g handles candidates it*8+g
    int g = lane >> 3, sub = lane & 7;
    const float* xvp = x + (size_t)R * FDIM + sub * 8;
    float4 xv0 = *reinterpret_cast<const float4*>(xvp);
    float4 xv1 = *reinterpret_cast<const float4*>(xvp + 4);
    float xv[8] = {xv0.x, xv0.y, xv0.z, xv0.w, xv1.x, xv1.y, xv1.z, xv1.w};
    int rounds = (base + 7) >> 3;
    for (int it = 0; it < rounds; ++it) {
      int c = it * 8 + g;
      unsigned int pk = pool[wave][c < base ? c : 0];
      int w = (int)(pk & 0xFFFFu);
      const float* xwp = x + (bbase + (unsigned int)w) * FDIM + sub * 8;
      float4 b0 = *reinterpret_cast<const float4*>(xwp);
      float4 b1 = *reinterpret_cast<const float4*>(xwp + 4);
      float dot = xv[0] * b0.x;
      dot = fmaf(xv[1], b0.y, dot); dot = fmaf(xv[2], b0.z, dot);
      dot = fmaf(xv[3], b0.w, dot); dot = fmaf(xv[4], b1.x, dot);
      dot = fmaf(xv[5], b1.y, dot); dot = fmaf(xv[6], b1.z, dot);
      dot = fmaf(xv[7], b1.w, dot);
      dot += __shfl_xor(dot, 1);
      dot += __shfl_xor(dot, 2);
      dot += __shfl_xor(dot, 4);
      float dx = fmaf(-2.0f, dot, sq[bbase + (unsigned int)w]);
      if (sub == 0 && c < base)
        pool2[wave][c] = ((u64)f2sort(dx) << 32) | (unsigned int)w;
    }
    lds_fence();
    u64 keyA = (lane < base) ? pool2[wave][lane] : ~0ULL;
    if (base <= 64) {
#pragma unroll
      for (int k = 2; k <= 64; k <<= 1) {
#pragma unroll
        for (int j = k >> 1; j > 0; j >>= 1) {
          u64 o = __shfl_xor(keyA, j);
          bool keep_min = ((lane & k) == 0) == ((lane & j) == 0);
          bool less = keyA < o;
          keyA = (keep_min == less) ? keyA : o;
        }
      }
      if (lane >= 1 && lane <= KNN)
        idxout[(size_t)R * KNN + (lane - 1)] = (int)(unsigned int)(keyA & 0xFFFFFFFFu);
    } else {
      u64 keyB = (64 + lane < base) ? pool2[wave][64 + lane] : ~0ULL;
#pragma unroll
      for (int k = 2; k <= 64; k <<= 1) {
#pragma unroll
        for (int j = k >> 1; j > 0; j >>= 1) {
          u64 oA = __shfl_xor(keyA, j);
          bool keep_min = ((lane & k) == 0) == ((lane & j) == 0);
          keyA = (keep_min == (keyA < oA)) ? keyA : oA;
          u64 oB = __shfl_xor(keyB, j);
          keyB = (keep_min == (keyB < oB)) ? keyB : oB;
        }
      }
      // merge: A asc + reverse(B asc) -> elementwise min is bitonic & holds smallest 64
      u64 keyBr = __shfl(keyB, 63 - lane);
      u64 mnk = keyA < keyBr ? keyA : keyBr;
#pragma unroll
      for (int j = 32; j > 0; j >>= 1) {
        u64 o = __shfl_xor(mnk, j);
        bool keep_min = (lane & j) == 0;
        mnk = (keep_min == (mnk < o)) ? mnk : o;
      }
      if (lane >= 1 && lane <= KNN)
        idxout[(size_t)R * KNN + (lane - 1)] = (int)(unsigned int)(mnk & 0xFFFFFFFFu);
    }
  } else {
    // exhaustive exact fallback (pathological only): recompute full row in fp32
    sXv[wave][lane] = x[(size_t)R * FDIM + lane];
    lds_fence();
    unsigned int sve[32];
#pragma unroll 1
    for (int s = 0; s < 4; ++s)
#pragma unroll 1
      for (int j = 0; j < 8; ++j) {
        int w = s * 512 + lane * 8 + j;
        const float* xw = x + (bbase + (unsigned int)w) * FDIM;
        float dot = 0.0f;
        for (int f = 0; f < 64; ++f) dot = fmaf(sXv[wave][f], xw[f], dot);
        sve[s * 8 + j] = f2sort(fmaf(-2.0f, dot, sq[bbase + (unsigned int)w]));
      }
    unsigned int removed = 0;
    for (int it = 0; it < KNN + 1; ++it) {
      u64 m = ~0ULL;
#pragma unroll
      for (int r = 0; r < 32; ++r) {
        u64 key = ((u64)sve[r] << 32) | (unsigned int)((r >> 3) * 512 + lane * 8 + (r & 7));
        bool alive = ((removed >> r) & 1u) == 0u;
        if (alive && key < m) m = key;
      }
      u64 gk = m;
#pragma unroll
      for (int off = 32; off; off >>= 1) {
        u64 o = __shfl_xor(gk, off);
        gk = (o < gk) ? o : gk;
      }
      if (it > 0 && lane == 0) idxout[(size_t)R * KNN + (it - 1)] = (int)(unsigned int)(gk & 0xFFFFFFFFu);
#pragma unroll
      for (int r = 0; r < 32; ++r) {
        u64 key = ((u64)sve[r] << 32) | (unsigned int)((r >> 3) * 512 + lane * 8 + (r & 7));
        if (key == gk) removed |= (1u << r);
      }
    }
  }
}

// ---------------- fused layers 2,3 + max aggregation ----------------
__global__ __launch_bounds__(256) void mlp_kernel(const float* __restrict__ U,
                                                  const unsigned short* __restrict__ P,
                                                  const int* __restrict__ idx,
                                                  const float* __restrict__ W2,
                                                  const float* __restrict__ b2,
                                                  const float* __restrict__ W3,
                                                  const float* __restrict__ b3,
                                                  float* __restrict__ out, int V) {
  __shared__ __align__(16) unsigned short sW2T[HDIM * HDIM];
  __shared__ __align__(16) unsigned short sW3T[HDIM * HDIM];
  __shared__ __align__(16) unsigned short sScr[4][2048];
  int t = threadIdx.x;
  for (int e = t; e < HDIM * HDIM; e += 256) {
    int i = e >> 6, j = e & 63;
    sW2T[swzi(j, i, 64)] = f2bf(W2[e]);
    int s = (i & 15) * 4 + (i >> 4);
    sW3T[swzi(j, s, 64)] = f2bf(W3[e]);
  }
  __syncthreads();

  int wv = t >> 6, lane = t & 63;
  int q = lane >> 4, cl = lane & 15;
  int g = lane >> 3, sub = lane & 7;
  unsigned short* scr = &sScr[wv][0];
  float bias2[4], bias3[4];
#pragma unroll
  for (int nt = 0; nt < 4; ++nt) {
    bias2[nt] = b2[nt * 16 + cl];
    bias3[nt] = b3[nt * 16 + cl];
  }

  for (int vi = 0; vi < 4; ++vi) {
    int v = blockIdx.x * 16 + wv * 4 + vi;
    int b = v / V;
    size_t bbase = (size_t)b * V;
    int myidx = (lane < KNN) ? idx[(size_t)v * KNN + lane] : 0;
    const float* up = U + (size_t)v * 64 + sub * 8;
    float4 u0 = *reinterpret_cast<const float4*>(up);
    float4 u1 = *reinterpret_cast<const float4*>(up + 4);
    float uu[8] = {u0.x, u0.y, u0.z, u0.w, u1.x, u1.y, u1.z, u1.w};

#pragma unroll
    for (int it = 0; it < 4; ++it) {
      int r = it * 8 + g;
      int kk = (r < KNN) ? r : (KNN - 1);
      int nb = __shfl(myidx, kk);
      const unsigned short* pp = P + (bbase + (unsigned int)nb) * 64 + sub * 8;
      s8v p8 = *reinterpret_cast<const s8v*>(pp);
      s8v hv;
#pragma unroll
      for (int j = 0; j < 8; ++j) {
        float f = uu[j] - bf2f((unsigned short)p8[j]);
        hv[j] = (short)f2bf(fmaxf(f, 0.0f));
      }
      *reinterpret_cast<s8v*>(&scr[swzi(r, sub * 8, 64)]) = hv;
    }
    lds_fence();

    s8v af2[2][2];
#pragma unroll
    for (int mt = 0; mt < 2; ++mt)
#pragma unroll
      for (int ks = 0; ks < 2; ++ks)
        af2[mt][ks] = *reinterpret_cast<const s8v*>(&scr[swzi(mt * 16 + cl, ks * 32 + q * 8, 64)]);
    f4v acc2[2][4];
#pragma unroll
    for (int mt = 0; mt < 2; ++mt)
#pragma unroll
      for (int nt = 0; nt < 4; ++nt) {
        f4v a0 = {bias2[nt], bias2[nt], bias2[nt], bias2[nt]};
        acc2[mt][nt] = a0;
      }
#pragma unroll
    for (int ks = 0; ks < 2; ++ks)
#pragma unroll
      for (int nt = 0; nt < 4; ++nt) {
        s8v wf = *reinterpret_cast<const s8v*>(&sW2T[swzi(nt * 16 + cl, ks * 32 + q * 8, 64)]);
        acc2[0][nt] = __builtin_amdgcn_mfma_f32_16x16x32_bf16(af2[0][ks], wf, acc2[0][nt], 0, 0, 0);
        acc2[1][nt] = __builtin_amdgcn_mfma_f32_16x16x32_bf16(af2[1][ks], wf, acc2[1][nt], 0, 0, 0);
      }
    lds_fence();
#pragma unroll
    for (int mt = 0; mt < 2; ++mt)
#pragma unroll
      for (int i = 0; i < 4; ++i) {
        int m = mt * 16 + q * 4 + i;
        u64 pk = 0;
#pragma unroll
        for (int nt = 0; nt < 4; ++nt) {
          u64 hb = f2bf(fmaxf(acc2[mt][nt][i], 0.0f));
          pk |= hb << (16 * nt);
        }
        *reinterpret_cast<u64*>(&scr[swzi(m, cl * 4, 64)]) = pk;
      }
    lds_fence();

    s8v af3[2][2];
#pragma unroll
    for (int mt = 0; mt < 2; ++mt)
#pragma unroll
      for (int ks = 0; ks < 2; ++ks)
        af3[mt][ks] = *reinterpret_cast<const s8v*>(&scr[swzi(mt * 16 + cl, ks * 32 + q * 8, 64)]);
    f4v acc3[2][4];
#pragma unroll
    for (int mt = 0; mt < 2; ++mt)
#pragma unroll
      for (int nt = 0; nt < 4; ++nt) {
        f4v a0 = {bias3[nt], bias3[nt], bias3[nt], bias3[nt]};
        acc3[mt][nt] = a0;
      }
#pragma unroll
    for (int ks = 0; ks < 2; ++ks)
#pragma unroll
      for (int nt = 0; nt < 4; ++nt) {
        s8v wf = *reinterpret_cast<const s8v*>(&sW3T[swzi(nt * 16 + cl, ks * 32 + q * 8, 64)]);
        acc3[0][nt] = __builtin_amdgcn_mfma_f32_16x16x32_bf16(af3[0][ks], wf, acc3[0][nt], 0, 0, 0);
        acc3[1][nt] = __builtin_amdgcn_mfma_f32_16x16x32_bf16(af3[1][ks], wf, acc3[1][nt], 0, 0, 0);
      }

    float m[4] = {0.0f, 0.0f, 0.0f, 0.0f};
#pragma unroll
    for (int nt = 0; nt < 4; ++nt)
#pragma unroll
      for (int mt = 0; mt < 2; ++mt)
#pragma unroll
        for (int i = 0; i < 4; ++i) m[nt] = fmaxf(m[nt], acc3[mt][nt][i]);
#pragma unroll
    for (int nt = 0; nt < 4; ++nt) {
      m[nt] = fmaxf(m[nt], __shfl_xor(m[nt], 16));
      m[nt] = fmaxf(m[nt], __shfl_xor(m[nt], 32));
    }
    float outv = (q == 0) ? m[0] : (q == 1) ? m[1] : (q == 2) ? m[2] : m[3];
    out[(size_t)v * HDIM + lane] = outv;
  }
}

extern "C" void kernel_launch(void* const* d_in, const int* in_sizes, int n_in,
                              void* d_out, int out_size, void* d_ws, size_t ws_size,
                              hipStream_t stream) {
  const float* x  = (const float*)d_in[0];
  const float* W1 = (const float*)d_in[2];
  const float* b1 = (const float*)d_in[3];
  const float* W2 = (const float*)d_in[4];
  const float* b2 = (const float*)d_in[5];
  const float* W3 = (const float*)d_in[6];
  const float* b3 = (const float*)d_in[7];
  float* out = (float*)d_out;
  int N = in_sizes[0] / FDIM;      // 32768
  int B = in_sizes[1] - 1;         // 16
  int V = N / B;                   // 2048

  char* ws = (char*)d_ws;
  float* sqbuf = (float*)ws;
  size_t off = (size_t)N * sizeof(float);
  int* idxbuf = (int*)(ws + off);
  off += (size_t)N * KNN * sizeof(int);
  off = (off + 255) & ~(size_t)255;
  float* Ubuf = (float*)(ws + off);
  off += (size_t)N * 64 * sizeof(float);
  unsigned short* Pbuf = (unsigned short*)(ws + off);
  off += (size_t)N * 64 * sizeof(unsigned short);
  off = (off + 255) & ~(size_t)255;
  unsigned short* D16buf = (unsigned short*)(ws + off);
  size_t dcap = (ws_size > off) ? (ws_size - off) : 0;
  long long capRows = (long long)(dcap / ((size_t)V * sizeof(unsigned short)));
  capRows &= ~127LL;
  if (capRows > N) capRows = N;
  if (capRows < 128) capRows = 128;  // requires sufficient ws_size

  sq_kernel<<<N / 4, 256, 0, stream>>>(x, sqbuf);
  uP_kernel<<<N / 128, 256, 0, stream>>>(x, W1, b1, Ubuf, Pbuf);
  for (int R0 = 0; R0 < N; R0 += (int)capRows) {
    int nr = N - R0;
    if (nr > capRows) nr = (int)capRows;
    dim3 g(V / 128, nr / 128);
    dist16_kernel<<<g, 256, 0, stream>>>(x, sqbuf, D16buf, R0, V);
    topk16_kernel<<<nr / 4, 256, 0, stream>>>(D16buf, x, sqbuf, idxbuf, R0, nr, V);
  }
  mlp_kernel<<<N / 16, 256, 0, stream>>>(Ubuf, Pbuf, idxbuf, W2, b2, W3, b3, out, V);
}